// Round 9
// baseline (216.329 us; speedup 1.0000x reference)
//
#include <hip/hip_runtime.h>
#include <math.h>

#define HW 16384

typedef unsigned short u16;
typedef __attribute__((ext_vector_type(8))) short short8;
typedef __attribute__((ext_vector_type(16))) float f32x16;

union U16B {
  uint4 u;
  short8 v;
  u16 s[8];
};

__device__ inline u16 f2b(float f) {
  unsigned u = __float_as_uint(f);
  u += 0x7FFF + ((u >> 16) & 1);
  return (u16)(u >> 16);
}
__device__ inline float b2f(u16 h) {
  return __uint_as_float(((unsigned)h) << 16);
}

// ---------------------------------------------------------------------------
// Weight packing helpers (bf16 per-lane MFMA A-fragments).
// ---------------------------------------------------------------------------
__device__ inline u16 pack_frag(const float* __restrict__ w, int Cin, int O,
                                int OT, int d) {
  int j = d & 7;
  int lane = (d >> 3) & 63;
  int rest = d >> 9;
  int ot = rest % OT; rest /= OT;
  int ks = rest & 3; rest >>= 2;
  int kx = rest % 3; rest /= 3;
  int ky = rest % 3; int s = rest / 3;
  int och = ot * 32 + (lane & 31);
  int ch = s * 64 + ks * 16 + ((lane >> 5) << 3) + j;
  if (och >= O) return 0;
  return f2b(w[((size_t)och * Cin + ch) * 9 + ky * 3 + kx]);
}

__device__ inline u16 pack_def(const float* __restrict__ w, int d) {
  int j = d & 7;
  int lane = (d >> 3) & 63;
  int g = d >> 9;
  int ot = g & 1;
  int t = g >> 1;
  int ks = t & 3;
  int k = t >> 2;
  int och = ot * 32 + (lane & 31);
  int c = ks * 16 + ((lane >> 5) << 3) + j;
  return f2b(w[((size_t)och * 64 + c) * 9 + k]);
}

__device__ inline u16 pack_up(const float* __restrict__ w, int d) {
  int j = d & 7;
  int lane = (d >> 3) & 63;
  int g = d >> 9;
  int ot = g & 1;
  int rest = g >> 1;
  int ks = rest & 7;
  int t = rest >> 3;
  int och = ot * 32 + (lane & 31);
  int ci = ks * 16 + ((lane >> 5) << 3) + j;
  return f2b(w[((size_t)och * 128 + ci) * 4 + t]);
}

// ---------------------------------------------------------------------------
// setup_kernel = prep (weight packing) + cvt_nhwc (xl,xr) + cvt_xd, one launch.
// (unchanged — validated)
// ---------------------------------------------------------------------------
__global__ __launch_bounds__(256) void setup_kernel(
    const float* __restrict__ dl_w, const float* __restrict__ dr_w,
    const float* __restrict__ up_w, const float* __restrict__ cv_w,
    const float* __restrict__ offl_w, const float* __restrict__ offr_w,
    const float* __restrict__ r1a, const float* __restrict__ r1b,
    const float* __restrict__ r2a, const float* __restrict__ r2b,
    u16* __restrict__ wup, u16* __restrict__ wdl, u16* __restrict__ wdr,
    u16* __restrict__ wcv, u16* __restrict__ wofl, u16* __restrict__ wofr,
    u16* __restrict__ wr1a, u16* __restrict__ wr1b,
    u16* __restrict__ wr2a, u16* __restrict__ wr2b,
    const float* __restrict__ xl, const float* __restrict__ xr,
    u16* __restrict__ xlh, u16* __restrict__ xrh,
    const float* __restrict__ xd, u16* __restrict__ xdh) {
  __shared__ float sT[8448];
  int tid = threadIdx.x;
  int b = blockIdx.x;
  if (b < 1856) {
    int d = b * 256 + tid;
    if (d < 32768) { wup[d] = pack_up(up_w, d); return; }
    d -= 32768;
    if (d < 36864) { wdl[d] = pack_def(dl_w, d); return; }
    d -= 36864;
    if (d < 36864) { wdr[d] = pack_def(dr_w, d); return; }
    d -= 36864;
    if (d < 110592) { wcv[d] = pack_frag(cv_w, 192, 64, 2, d); return; }
    d -= 110592;
    if (d < 55296) { wofl[d] = pack_frag(offl_w, 192, 27, 1, d); return; }
    d -= 55296;
    if (d < 55296) { wofr[d] = pack_frag(offr_w, 192, 27, 1, d); return; }
    d -= 55296;
    if (d < 36864) { wr1a[d] = pack_frag(r1a, 64, 64, 2, d); return; }
    d -= 36864;
    if (d < 36864) { wr1b[d] = pack_frag(r1b, 64, 64, 2, d); return; }
    d -= 36864;
    if (d < 36864) { wr2a[d] = pack_frag(r2a, 64, 64, 2, d); return; }
    d -= 36864;
    if (d < 36864) { wr2b[d] = pack_frag(r2b, 64, 64, 2, d); return; }
    return;
  }
  b -= 1856;
  if (b < 512) {
    int y = b & 127;
    int pid = b >> 7;
    const float* src = (pid >> 1) ? xr : xl;
    u16* dst = (pid >> 1) ? xrh : xlh;
    int n = pid & 1;
#pragma unroll
    for (int i = 0; i < 8; ++i) {
      int q = tid + i * 256;
      int ch = q >> 5, pxq = q & 31;
      float4 v = *(const float4*)(src + ((size_t)(n * 64 + ch)) * HW + y * 128 + pxq * 4);
      *(float4*)&sT[ch * 132 + pxq * 4] = v;
    }
    __syncthreads();
    int px = tid >> 1, half = tid & 1;
    u16* op = dst + (((size_t)(n * 128 + y)) * 128 + px) * 64 + half * 32;
#pragma unroll
    for (int c = 0; c < 4; ++c) {
      uint4 v;
      int ob = (half * 32 + c * 8);
      v.x = (unsigned)f2b(sT[(ob + 0) * 132 + px]) | ((unsigned)f2b(sT[(ob + 1) * 132 + px]) << 16);
      v.y = (unsigned)f2b(sT[(ob + 2) * 132 + px]) | ((unsigned)f2b(sT[(ob + 3) * 132 + px]) << 16);
      v.z = (unsigned)f2b(sT[(ob + 4) * 132 + px]) | ((unsigned)f2b(sT[(ob + 5) * 132 + px]) << 16);
      v.w = (unsigned)f2b(sT[(ob + 6) * 132 + px]) | ((unsigned)f2b(sT[(ob + 7) * 132 + px]) << 16);
      *(uint4*)(op + c * 8) = v;
    }
    return;
  }
  b -= 512;
  {
    int r = b & 63;
    int n = b >> 6;
#pragma unroll
    for (int i = 0; i < 8; ++i) {
      int q = tid + i * 256;
      int ch = q >> 4, col4 = q & 15;
      float4 v = *(const float4*)(xd + ((size_t)(n * 128 + ch) * 64 + r) * 64 + col4 * 4);
      *(float4*)&sT[ch * 66 + col4 * 4] = v;
    }
    __syncthreads();
#pragma unroll
    for (int i = 0; i < 4; ++i) {
      int q = tid + i * 256;
      int col = q >> 4, cho = q & 15;
      uint4 v;
      int cb = cho * 8;
      v.x = (unsigned)f2b(sT[(cb + 0) * 66 + col]) | ((unsigned)f2b(sT[(cb + 1) * 66 + col]) << 16);
      v.y = (unsigned)f2b(sT[(cb + 2) * 66 + col]) | ((unsigned)f2b(sT[(cb + 3) * 66 + col]) << 16);
      v.z = (unsigned)f2b(sT[(cb + 4) * 66 + col]) | ((unsigned)f2b(sT[(cb + 5) * 66 + col]) << 16);
      v.w = (unsigned)f2b(sT[(cb + 6) * 66 + col]) | ((unsigned)f2b(sT[(cb + 7) * 66 + col]) << 16);
      *(uint4*)(xdh + (((size_t)(n * 64 + r)) * 64 + col) * 128 + cb) = v;
    }
  }
}

// ---------------------------------------------------------------------------
// Upsample+2x2 conv, 32-px blocks: 256 thr = 4 waves, wave = one tap t.
// grid = (128 rows * 4 pxq, n). 4-way LDS reduce by wave 0.
// ---------------------------------------------------------------------------
__global__ __launch_bounds__(256) void upconv_mf(
    const u16* __restrict__ xdh, const u16* __restrict__ wup,
    const float* __restrict__ bias, u16* __restrict__ outH) {
  __shared__ float s_red[3][2][16][64];
  const int tid = threadIdx.x;
  const int lane = tid & 63;
  const int t = tid >> 6;  // tap = wave id
  const int y = blockIdx.x >> 2;
  const int px0 = (blockIdx.x & 3) << 5;
  const int n = blockIdx.y;
  const int px = px0 + (lane & 31);
  const int h = lane >> 5;

  f32x16 acc0, acc1;
#pragma unroll
  for (int i = 0; i < 16; ++i) { acc0[i] = 0.f; acc1[i] = 0.f; }

  const u16* xb = xdh + ((size_t)n * 64 * 64) * 128;
  const int ty = t >> 1, tx = t & 1;
  const int row = min((y + ty) >> 1, 63);
  const int col = min((px + tx) >> 1, 63);
  const u16* src = xb + ((size_t)(row * 64 + col)) * 128;
#pragma unroll
  for (int ks = 0; ks < 8; ++ks) {
    U16B bf;
    bf.u = *(const uint4*)(src + ks * 16 + h * 8);
    const u16* wp = wup + ((size_t)((t * 8 + ks) * 2)) * 512 + lane * 8;
    U16B a0, a1;
    a0.u = *(const uint4*)wp;
    a1.u = *(const uint4*)(wp + 512);
    acc0 = __builtin_amdgcn_mfma_f32_32x32x16_bf16(a0.v, bf.v, acc0, 0, 0, 0);
    acc1 = __builtin_amdgcn_mfma_f32_32x32x16_bf16(a1.v, bf.v, acc1, 0, 0, 0);
  }

  if (t != 0) {
#pragma unroll
    for (int i = 0; i < 16; ++i) {
      s_red[t - 1][0][i][lane] = acc0[i];
      s_red[t - 1][1][i][lane] = acc1[i];
    }
  }
  __syncthreads();
  if (t == 0) {
    const bool zero = (y == 127) || (px == 127);
    const size_t pixb = (((size_t)(n * 128 + y)) * 128 + px) * 64;
#pragma unroll
    for (int ot = 0; ot < 2; ++ot) {
      f32x16 A = ot ? acc1 : acc0;
#pragma unroll
      for (int q = 0; q < 4; ++q) {
        int oo = ot * 32 + 8 * q + 4 * h;
        float v[4];
#pragma unroll
        for (int r = 0; r < 4; ++r) {
          int i = q * 4 + r;
          float s = A[i] + s_red[0][ot][i][lane] + s_red[1][ot][i][lane] +
                    s_red[2][ot][i][lane];
          v[r] = zero ? 0.f : (s + bias[oo + r]);
        }
        ushort4 hh;
        hh.x = f2b(v[0]); hh.y = f2b(v[1]); hh.z = f2b(v[2]); hh.w = f2b(v[3]);
        *(ushort4*)(outH + pixb + oo) = hh;
      }
    }
  }
}

// ---------------------------------------------------------------------------
// MFMA 3x3 conv, pad=1, direct-global-load (unchanged — validated).
// ---------------------------------------------------------------------------
template <int NSEG>
__global__ __launch_bounds__(512) void mfconv_d(
    const u16* __restrict__ in0, const u16* __restrict__ in1,
    const u16* __restrict__ in2, const u16* __restrict__ wpk,
    const float* __restrict__ bias, const u16* __restrict__ resh,
    float* __restrict__ outF, u16* __restrict__ outH,
    int OT, int O, int mode) {
  __shared__ float s_red[2][3][16][64];
  const int tid = threadIdx.x;
  const int lane = tid & 63;
  const int w = tid >> 6;
  const int p2 = w >> 2;
  const int kq = w & 3;
  const int y = blockIdx.x >> 1;
  const int xh0 = (blockIdx.x & 1) << 6;
  const int ot = blockIdx.y;
  const int n = blockIdx.z;
  const int px = xh0 + (p2 << 5) + (lane & 31);
  const int h = lane >> 5;

  f32x16 acc;
#pragma unroll
  for (int i = 0; i < 16; ++i) acc[i] = 0.f;

#pragma unroll
  for (int s = 0; s < NSEG; ++s) {
    const u16* sp = (s == 0) ? in0 : ((s == 1) ? in1 : in2);
    const u16* bn = sp + ((size_t)n * 128) * 128 * 64;
#pragma unroll
    for (int ky = 0; ky < 3; ++ky) {
      int r = y + ky - 1;
      if ((unsigned)r >= 128u) continue;
      const u16* rp = bn + (size_t)r * (128 * 64);
#pragma unroll
      for (int kx = 0; kx < 3; ++kx) {
        int col = px + kx - 1;
        bool valid = (unsigned)col < 128u;
        int colc = min(max(col, 0), 127);
        const u16* pp = rp + (size_t)colc * 64 + h * 8;
        U16B bf;
        bf.u = *(const uint4*)(pp + kq * 16);
        if (!valid) bf.u = make_uint4(0, 0, 0, 0);
        U16B a;
        a.u = *(const uint4*)(wpk +
              ((size_t)((((s * 3 + ky) * 3 + kx) * 4 + kq) * OT + ot)) * 512 +
              lane * 8);
        acc = __builtin_amdgcn_mfma_f32_32x32x16_bf16(a.v, bf.v, acc, 0, 0, 0);
      }
    }
  }

  if (kq != 0) {
#pragma unroll
    for (int i = 0; i < 16; ++i) s_red[p2][kq - 1][i][lane] = acc[i];
  }
  __syncthreads();
  if (kq == 0) {
#pragma unroll
    for (int i = 0; i < 16; ++i)
      acc[i] += s_red[p2][0][i][lane] + s_red[p2][1][i][lane] + s_red[p2][2][i][lane];
    const size_t pixb = ((size_t)(n * 128 + y)) * 128 + px;
    if (outH) {
#pragma unroll
      for (int q = 0; q < 4; ++q) {
        int oo = ot * 32 + 8 * q + 4 * h;
        float v[4];
#pragma unroll
        for (int r = 0; r < 4; ++r) v[r] = acc[q * 4 + r] + bias[oo + r];
        if (mode == 1) {
#pragma unroll
          for (int r = 0; r < 4; ++r) v[r] = fmaxf(v[r], 0.f);
        } else if (mode == 3) {
          ushort4 rv = *(const ushort4*)(resh + pixb * 64 + oo);
          v[0] += b2f(rv.x); v[1] += b2f(rv.y); v[2] += b2f(rv.z); v[3] += b2f(rv.w);
        }
        ushort4 hh;
        hh.x = f2b(v[0]); hh.y = f2b(v[1]); hh.z = f2b(v[2]); hh.w = f2b(v[3]);
        *(ushort4*)(outH + pixb * 64 + oo) = hh;
      }
    } else {
#pragma unroll
      for (int q = 0; q < 4; ++q) {
        int oo = ot * 32 + 8 * q + 4 * h;
#pragma unroll
        for (int r = 0; r < 4; ++r) {
          int och = oo + r;
          if (och >= O) continue;
          float v = acc[q * 4 + r] + bias[och];
          if (mode == 3) v += b2f(resh[pixb * 64 + och]);
          outF[((size_t)(n * O + och)) * HW + y * 128 + px] = v;
        }
      }
    }
  }
}

// ---------------------------------------------------------------------------
// Fused offset-conv + modulated deformable conv, 32-px blocks.
// 256 thr = 4 waves. Phase 1: wave = ks-quarter (27 MFMA). Phase 2: wave =
// tap-group {0-2},{3-4},{5-6},{7-8}. Both phases 4-way LDS reduce by wave 0.
// grid = (128 rows * 4 pxq, n).
// ---------------------------------------------------------------------------
__global__ __launch_bounds__(256) void deform_fused(
    const u16* __restrict__ in0, const u16* __restrict__ in1,
    const u16* __restrict__ in2, const u16* __restrict__ woff,
    const float* __restrict__ boff, const u16* __restrict__ xh,
    const u16* __restrict__ wdef, const float* __restrict__ bdef,
    u16* __restrict__ outH) {
  __shared__ float s_off[27][32];
  __shared__ float s_red[3][2][16][64];
  const int tid = threadIdx.x;
  const int lane = tid & 63;
  const int kg = tid >> 6;  // wave id
  const int y = blockIdx.x >> 2;
  const int px0 = (blockIdx.x & 3) << 5;
  const int n = blockIdx.y;
  const int lx = lane & 31;
  const int px = px0 + lx;
  const int h = lane >> 5;

  // ---- Phase 1: offset conv (kg = ks quarter) ----
  {
    f32x16 acc;
#pragma unroll
    for (int i = 0; i < 16; ++i) acc[i] = 0.f;
#pragma unroll
    for (int s = 0; s < 3; ++s) {
      const u16* sp = (s == 0) ? in0 : ((s == 1) ? in1 : in2);
      const u16* bn = sp + ((size_t)n * 128) * 128 * 64;
#pragma unroll
      for (int ky = 0; ky < 3; ++ky) {
        int r = y + ky - 1;
        if ((unsigned)r >= 128u) continue;
        const u16* rp = bn + (size_t)r * (128 * 64);
#pragma unroll
        for (int kx = 0; kx < 3; ++kx) {
          int col = px + kx - 1;
          bool valid = (unsigned)col < 128u;
          int colc = min(max(col, 0), 127);
          U16B bf;
          bf.u = *(const uint4*)(rp + (size_t)colc * 64 + kg * 16 + h * 8);
          if (!valid) bf.u = make_uint4(0, 0, 0, 0);
          U16B a;
          a.u = *(const uint4*)(woff +
                ((size_t)(((s * 3 + ky) * 3 + kx) * 4 + kg)) * 512 + lane * 8);
          acc = __builtin_amdgcn_mfma_f32_32x32x16_bf16(a.v, bf.v, acc, 0, 0, 0);
        }
      }
    }
    if (kg != 0) {
#pragma unroll
      for (int i = 0; i < 16; ++i) s_red[kg - 1][0][i][lane] = acc[i];
    }
    __syncthreads();
    if (kg == 0) {
#pragma unroll
      for (int q = 0; q < 4; ++q) {
#pragma unroll
        for (int r = 0; r < 4; ++r) {
          int och = 8 * q + 4 * h + r;
          if (och < 27) {
            int i = q * 4 + r;
            float v = acc[i] + s_red[0][0][i][lane] + s_red[1][0][i][lane] +
                      s_red[2][0][i][lane] + boff[och];
            if (och >= 18) v = 1.f / (1.f + expf(-v));
            s_off[och][lx] = v;
          }
        }
      }
    }
  }
  __syncthreads();

  // ---- Phase 2: deform gather + GEMM (kg = tap group) ----
  f32x16 acc0, acc1;
#pragma unroll
  for (int i = 0; i < 16; ++i) { acc0[i] = 0.f; acc1[i] = 0.f; }

  const u16* xb = xh + ((size_t)n * HW) * 64;
  const int kstart = kg ? (1 + 2 * kg) : 0;
  const int kcnt = kg ? 2 : 3;

#pragma unroll
  for (int kk = 0; kk < 3; ++kk) {
    if (kk >= kcnt) break;
    const int k = kstart + kk;
    const int ky = k / 3 - 1, kx = k % 3 - 1;
    float dy = s_off[2 * k][lx];
    float dx = s_off[2 * k + 1][lx];
    float m = s_off[18 + k][lx];
    float py = dy + (float)(y + ky);
    float pxf = dx + (float)(px + kx);
    float fy = floorf(py), fxx = floorf(pxf);
    float wy = py - fy, wx = pxf - fxx;
    int iy0 = (int)fy, ix0 = (int)fxx;
    bool vy0 = (unsigned)iy0 < 128u, vy1 = (unsigned)(iy0 + 1) < 128u;
    bool vx0 = (unsigned)ix0 < 128u, vx1 = (unsigned)(ix0 + 1) < 128u;
    float omwy = 1.f - wy, omwx = 1.f - wx;
    float f00 = (vy0 && vx0) ? omwy * omwx * m : 0.f;
    float f01 = (vy0 && vx1) ? omwy * wx * m : 0.f;
    float f10 = (vy1 && vx0) ? wy * omwx * m : 0.f;
    float f11 = (vy1 && vx1) ? wy * wx * m : 0.f;
    int y0c = min(max(iy0, 0), 127), y1c = min(max(iy0 + 1, 0), 127);
    int x0c = min(max(ix0, 0), 127), x1c = min(max(ix0 + 1, 0), 127);
    const u16* r00 = xb + ((size_t)(y0c * 128 + x0c)) * 64;
    const u16* r01 = xb + ((size_t)(y0c * 128 + x1c)) * 64;
    const u16* r10 = xb + ((size_t)(y1c * 128 + x0c)) * 64;
    const u16* r11 = xb + ((size_t)(y1c * 128 + x1c)) * 64;
#pragma unroll
    for (int ks = 0; ks < 4; ++ks) {
      const int co = ks * 16 + h * 8;
      U16B u00, u01, u10, u11;
      u00.u = *(const uint4*)(r00 + co);
      u01.u = *(const uint4*)(r01 + co);
      u10.u = *(const uint4*)(r10 + co);
      u11.u = *(const uint4*)(r11 + co);
      unsigned dw[4];
#pragma unroll
      for (int jj = 0; jj < 4; ++jj) {
        float s0 = f00 * b2f(u00.s[2 * jj]) + f01 * b2f(u01.s[2 * jj]) +
                   f10 * b2f(u10.s[2 * jj]) + f11 * b2f(u11.s[2 * jj]);
        float s1 = f00 * b2f(u00.s[2 * jj + 1]) + f01 * b2f(u01.s[2 * jj + 1]) +
                   f10 * b2f(u10.s[2 * jj + 1]) + f11 * b2f(u11.s[2 * jj + 1]);
        dw[jj] = (unsigned)f2b(s0) | ((unsigned)f2b(s1) << 16);
      }
      U16B bf;
      bf.u = make_uint4(dw[0], dw[1], dw[2], dw[3]);
      const u16* wp = wdef + ((size_t)((k * 4 + ks) * 2)) * 512 + lane * 8;
      U16B a0, a1;
      a0.u = *(const uint4*)wp;
      a1.u = *(const uint4*)(wp + 512);
      acc0 = __builtin_amdgcn_mfma_f32_32x32x16_bf16(a0.v, bf.v, acc0, 0, 0, 0);
      acc1 = __builtin_amdgcn_mfma_f32_32x32x16_bf16(a1.v, bf.v, acc1, 0, 0, 0);
    }
  }

  if (kg != 0) {
#pragma unroll
    for (int i = 0; i < 16; ++i) {
      s_red[kg - 1][0][i][lane] = acc0[i];
      s_red[kg - 1][1][i][lane] = acc1[i];
    }
  }
  __syncthreads();
  if (kg == 0) {
    const size_t pixb = (((size_t)(n * 128 + y)) * 128 + px) * 64;
#pragma unroll
    for (int ot = 0; ot < 2; ++ot) {
      f32x16 A = ot ? acc1 : acc0;
#pragma unroll
      for (int q = 0; q < 4; ++q) {
        int oo = ot * 32 + 8 * q + 4 * h;
        float v[4];
#pragma unroll
        for (int r = 0; r < 4; ++r) {
          int i = q * 4 + r;
          v[r] = A[i] + s_red[0][ot][i][lane] + s_red[1][ot][i][lane] +
                 s_red[2][ot][i][lane] + bdef[oo + r];
        }
        ushort4 hh;
        hh.x = f2b(v[0]); hh.y = f2b(v[1]); hh.z = f2b(v[2]); hh.w = f2b(v[3]);
        *(ushort4*)(outH + pixb + oo) = hh;
      }
    }
  }
}

// ---------------------------------------------------------------------------
extern "C" void kernel_launch(void* const* d_in, const int* in_sizes, int n_in,
                              void* d_out, int out_size, void* d_ws, size_t ws_size,
                              hipStream_t stream) {
  const float* xd = (const float*)d_in[0];
  const float* xl = (const float*)d_in[1];
  const float* xr = (const float*)d_in[2];
  const float* up_w = (const float*)d_in[3];
  const float* up_b = (const float*)d_in[4];
  const float* offl_w = (const float*)d_in[5];
  const float* offl_b = (const float*)d_in[6];
  const float* dl_w = (const float*)d_in[7];
  const float* dl_b = (const float*)d_in[8];
  const float* offr_w = (const float*)d_in[9];
  const float* offr_b = (const float*)d_in[10];
  const float* dr_w = (const float*)d_in[11];
  const float* dr_b = (const float*)d_in[12];
  const float* cv_w = (const float*)d_in[13];
  const float* cv_b = (const float*)d_in[14];
  const float* rb1_w1 = (const float*)d_in[15];
  const float* rb1_w2 = (const float*)d_in[16];
  const float* rb2_w1 = (const float*)d_in[17];
  const float* rb2_w2 = (const float*)d_in[18];
  const float* rb1_b1 = (const float*)d_in[19];
  const float* rb1_b2 = (const float*)d_in[20];
  const float* rb2_b1 = (const float*)d_in[21];
  const float* rb2_b2 = (const float*)d_in[22];

  float* ws = (float*)d_ws;
  u16* hb = (u16*)(ws + 1769472);
  u16* xlh = hb;                   // 2097152 each
  u16* xrh = hb + 2097152;
  u16* xdph = hb + 4194304;
  u16* xl2h = hb + 6291456;
  u16* xr2h = hb + 8388608;
  u16* t0h = hb + 10485760;
  u16* t1h = hb + 12582912;
  u16* t2h = hb + 14680064;
  u16* t3h = hb + 16777216;
  u16* xdh = hb + 18874368;        // 1048576 (2*64*64*128)
  u16* wcv = hb + 19922944;        // 110592
  u16* wofl = hb + 20033536;       // 55296
  u16* wofr = hb + 20088832;       // 55296
  u16* wr1a = hb + 20144128;       // 36864
  u16* wr1b = hb + 20180992;
  u16* wr2a = hb + 20217856;
  u16* wr2b = hb + 20254720;
  u16* wdl = hb + 20291584;        // 36864
  u16* wdr = hb + 20328448;        // 36864
  u16* wup = hb + 20365312;        // 32768
  float* outp = (float*)d_out;

  hipLaunchKernelGGL(setup_kernel, dim3(2496), dim3(256), 0, stream,
                     dl_w, dr_w, up_w, cv_w, offl_w, offr_w, rb1_w1, rb1_w2,
                     rb2_w1, rb2_w2, wup, wdl, wdr, wcv, wofl, wofr, wr1a,
                     wr1b, wr2a, wr2b, xl, xr, xlh, xrh, xd, xdh);
  hipLaunchKernelGGL(upconv_mf, dim3(512, 2), dim3(256), 0, stream,
                     xdh, wup, up_b, xdph);
  hipLaunchKernelGGL(deform_fused, dim3(512, 2), dim3(256), 0, stream,
                     xlh, xrh, xdph, wofl, offl_b, xlh, wdl, dl_b, xl2h);
  hipLaunchKernelGGL(deform_fused, dim3(512, 2), dim3(256), 0, stream,
                     xl2h, xrh, xdph, wofr, offr_b, xrh, wdr, dr_b, xr2h);
  hipLaunchKernelGGL(mfconv_d<3>, dim3(256, 2, 2), dim3(512), 0, stream,
                     xl2h, xr2h, xdph, wcv, cv_b, (const u16*)nullptr,
                     (float*)nullptr, t0h, 2, 64, 1);
  hipLaunchKernelGGL(mfconv_d<1>, dim3(256, 2, 2), dim3(512), 0, stream,
                     t0h, (const u16*)nullptr, (const u16*)nullptr, wr1a,
                     rb1_b1, (const u16*)nullptr, (float*)nullptr, t1h,
                     2, 64, 1);
  hipLaunchKernelGGL(mfconv_d<1>, dim3(256, 2, 2), dim3(512), 0, stream,
                     t1h, (const u16*)nullptr, (const u16*)nullptr, wr1b,
                     rb1_b2, t0h, (float*)nullptr, t2h, 2, 64, 3);
  hipLaunchKernelGGL(mfconv_d<1>, dim3(256, 2, 2), dim3(512), 0, stream,
                     t2h, (const u16*)nullptr, (const u16*)nullptr, wr2a,
                     rb2_b1, (const u16*)nullptr, (float*)nullptr, t3h,
                     2, 64, 1);
  hipLaunchKernelGGL(mfconv_d<1>, dim3(256, 2, 2), dim3(512), 0, stream,
                     t3h, (const u16*)nullptr, (const u16*)nullptr, wr2b,
                     rb2_b2, t2h, outp, (u16*)nullptr, 2, 64, 3);
}

// Round 10
// 194.007 us; speedup vs baseline: 1.1151x; 1.1151x over previous
//
#include <hip/hip_runtime.h>
#include <math.h>

#define HW 16384

typedef unsigned short u16;
typedef __attribute__((ext_vector_type(8))) short short8;
typedef __attribute__((ext_vector_type(16))) float f32x16;

union U16B {
  uint4 u;
  short8 v;
  u16 s[8];
};

__device__ inline u16 f2b(float f) {
  unsigned u = __float_as_uint(f);
  u += 0x7FFF + ((u >> 16) & 1);
  return (u16)(u >> 16);
}
__device__ inline float b2f(u16 h) {
  return __uint_as_float(((unsigned)h) << 16);
}

// ---------------------------------------------------------------------------
// Weight packing helpers (bf16 per-lane MFMA A-fragments).
// ---------------------------------------------------------------------------
__device__ inline u16 pack_frag(const float* __restrict__ w, int Cin, int O,
                                int OT, int d) {
  int j = d & 7;
  int lane = (d >> 3) & 63;
  int rest = d >> 9;
  int ot = rest % OT; rest /= OT;
  int ks = rest & 3; rest >>= 2;
  int kx = rest % 3; rest /= 3;
  int ky = rest % 3; int s = rest / 3;
  int och = ot * 32 + (lane & 31);
  int ch = s * 64 + ks * 16 + ((lane >> 5) << 3) + j;
  if (och >= O) return 0;
  return f2b(w[((size_t)och * Cin + ch) * 9 + ky * 3 + kx]);
}

__device__ inline u16 pack_def(const float* __restrict__ w, int d) {
  int j = d & 7;
  int lane = (d >> 3) & 63;
  int g = d >> 9;
  int ot = g & 1;
  int t = g >> 1;
  int ks = t & 3;
  int k = t >> 2;
  int och = ot * 32 + (lane & 31);
  int c = ks * 16 + ((lane >> 5) << 3) + j;
  return f2b(w[((size_t)och * 64 + c) * 9 + k]);
}

__device__ inline u16 pack_up(const float* __restrict__ w, int d) {
  int j = d & 7;
  int lane = (d >> 3) & 63;
  int g = d >> 9;
  int ot = g & 1;
  int rest = g >> 1;
  int ks = rest & 7;
  int t = rest >> 3;
  int och = ot * 32 + (lane & 31);
  int ci = ks * 16 + ((lane >> 5) << 3) + j;
  return f2b(w[((size_t)och * 128 + ci) * 4 + t]);
}

// ---------------------------------------------------------------------------
// setup_kernel = prep (weight packing) + cvt_nhwc (xl,xr) + cvt_xd, one launch.
// (unchanged — validated)
// ---------------------------------------------------------------------------
__global__ __launch_bounds__(256) void setup_kernel(
    const float* __restrict__ dl_w, const float* __restrict__ dr_w,
    const float* __restrict__ up_w, const float* __restrict__ cv_w,
    const float* __restrict__ offl_w, const float* __restrict__ offr_w,
    const float* __restrict__ r1a, const float* __restrict__ r1b,
    const float* __restrict__ r2a, const float* __restrict__ r2b,
    u16* __restrict__ wup, u16* __restrict__ wdl, u16* __restrict__ wdr,
    u16* __restrict__ wcv, u16* __restrict__ wofl, u16* __restrict__ wofr,
    u16* __restrict__ wr1a, u16* __restrict__ wr1b,
    u16* __restrict__ wr2a, u16* __restrict__ wr2b,
    const float* __restrict__ xl, const float* __restrict__ xr,
    u16* __restrict__ xlh, u16* __restrict__ xrh,
    const float* __restrict__ xd, u16* __restrict__ xdh) {
  __shared__ float sT[8448];
  int tid = threadIdx.x;
  int b = blockIdx.x;
  if (b < 1856) {
    int d = b * 256 + tid;
    if (d < 32768) { wup[d] = pack_up(up_w, d); return; }
    d -= 32768;
    if (d < 36864) { wdl[d] = pack_def(dl_w, d); return; }
    d -= 36864;
    if (d < 36864) { wdr[d] = pack_def(dr_w, d); return; }
    d -= 36864;
    if (d < 110592) { wcv[d] = pack_frag(cv_w, 192, 64, 2, d); return; }
    d -= 110592;
    if (d < 55296) { wofl[d] = pack_frag(offl_w, 192, 27, 1, d); return; }
    d -= 55296;
    if (d < 55296) { wofr[d] = pack_frag(offr_w, 192, 27, 1, d); return; }
    d -= 55296;
    if (d < 36864) { wr1a[d] = pack_frag(r1a, 64, 64, 2, d); return; }
    d -= 36864;
    if (d < 36864) { wr1b[d] = pack_frag(r1b, 64, 64, 2, d); return; }
    d -= 36864;
    if (d < 36864) { wr2a[d] = pack_frag(r2a, 64, 64, 2, d); return; }
    d -= 36864;
    if (d < 36864) { wr2b[d] = pack_frag(r2b, 64, 64, 2, d); return; }
    return;
  }
  b -= 1856;
  if (b < 512) {
    int y = b & 127;
    int pid = b >> 7;
    const float* src = (pid >> 1) ? xr : xl;
    u16* dst = (pid >> 1) ? xrh : xlh;
    int n = pid & 1;
#pragma unroll
    for (int i = 0; i < 8; ++i) {
      int q = tid + i * 256;
      int ch = q >> 5, pxq = q & 31;
      float4 v = *(const float4*)(src + ((size_t)(n * 64 + ch)) * HW + y * 128 + pxq * 4);
      *(float4*)&sT[ch * 132 + pxq * 4] = v;
    }
    __syncthreads();
    int px = tid >> 1, half = tid & 1;
    u16* op = dst + (((size_t)(n * 128 + y)) * 128 + px) * 64 + half * 32;
#pragma unroll
    for (int c = 0; c < 4; ++c) {
      uint4 v;
      int ob = (half * 32 + c * 8);
      v.x = (unsigned)f2b(sT[(ob + 0) * 132 + px]) | ((unsigned)f2b(sT[(ob + 1) * 132 + px]) << 16);
      v.y = (unsigned)f2b(sT[(ob + 2) * 132 + px]) | ((unsigned)f2b(sT[(ob + 3) * 132 + px]) << 16);
      v.z = (unsigned)f2b(sT[(ob + 4) * 132 + px]) | ((unsigned)f2b(sT[(ob + 5) * 132 + px]) << 16);
      v.w = (unsigned)f2b(sT[(ob + 6) * 132 + px]) | ((unsigned)f2b(sT[(ob + 7) * 132 + px]) << 16);
      *(uint4*)(op + c * 8) = v;
    }
    return;
  }
  b -= 512;
  {
    int r = b & 63;
    int n = b >> 6;
#pragma unroll
    for (int i = 0; i < 8; ++i) {
      int q = tid + i * 256;
      int ch = q >> 4, col4 = q & 15;
      float4 v = *(const float4*)(xd + ((size_t)(n * 128 + ch) * 64 + r) * 64 + col4 * 4);
      *(float4*)&sT[ch * 66 + col4 * 4] = v;
    }
    __syncthreads();
#pragma unroll
    for (int i = 0; i < 4; ++i) {
      int q = tid + i * 256;
      int col = q >> 4, cho = q & 15;
      uint4 v;
      int cb = cho * 8;
      v.x = (unsigned)f2b(sT[(cb + 0) * 66 + col]) | ((unsigned)f2b(sT[(cb + 1) * 66 + col]) << 16);
      v.y = (unsigned)f2b(sT[(cb + 2) * 66 + col]) | ((unsigned)f2b(sT[(cb + 3) * 66 + col]) << 16);
      v.z = (unsigned)f2b(sT[(cb + 4) * 66 + col]) | ((unsigned)f2b(sT[(cb + 5) * 66 + col]) << 16);
      v.w = (unsigned)f2b(sT[(cb + 6) * 66 + col]) | ((unsigned)f2b(sT[(cb + 7) * 66 + col]) << 16);
      *(uint4*)(xdh + (((size_t)(n * 64 + r)) * 64 + col) * 128 + cb) = v;
    }
  }
}

// ---------------------------------------------------------------------------
// Fused nearest-x2 upsample + 2x2 conv + zero-pad via gather + MFMA.
// (reverted to R7 512-thread shape — validated at 196 µs total)
// ---------------------------------------------------------------------------
__global__ __launch_bounds__(512) void upconv_mf(
    const u16* __restrict__ xdh, const u16* __restrict__ wup,
    const float* __restrict__ bias, u16* __restrict__ outH) {
  __shared__ float s_red[4][2][16][64];
  const int tid = threadIdx.x;
  const int lane = tid & 63;
  const int w = tid >> 6;
  const int p2 = w >> 1;
  const int th = w & 1;
  const int y = blockIdx.x;
  const int n = blockIdx.y;
  const int px = (p2 << 5) + (lane & 31);
  const int h = lane >> 5;

  f32x16 acc0, acc1;
#pragma unroll
  for (int i = 0; i < 16; ++i) { acc0[i] = 0.f; acc1[i] = 0.f; }

  const u16* xb = xdh + ((size_t)n * 64 * 64) * 128;

#pragma unroll
  for (int tt = 0; tt < 2; ++tt) {
    const int t = th * 2 + tt;
    const int ty = t >> 1, tx = t & 1;
    const int row = min((y + ty) >> 1, 63);
    const int col = min((px + tx) >> 1, 63);
    const u16* src = xb + ((size_t)(row * 64 + col)) * 128;
#pragma unroll
    for (int ks = 0; ks < 8; ++ks) {
      U16B bf;
      bf.u = *(const uint4*)(src + ks * 16 + h * 8);
      const u16* wp = wup + ((size_t)((t * 8 + ks) * 2)) * 512 + lane * 8;
      U16B a0, a1;
      a0.u = *(const uint4*)wp;
      a1.u = *(const uint4*)(wp + 512);
      acc0 = __builtin_amdgcn_mfma_f32_32x32x16_bf16(a0.v, bf.v, acc0, 0, 0, 0);
      acc1 = __builtin_amdgcn_mfma_f32_32x32x16_bf16(a1.v, bf.v, acc1, 0, 0, 0);
    }
  }

  if (th == 1) {
#pragma unroll
    for (int i = 0; i < 16; ++i) {
      s_red[p2][0][i][lane] = acc0[i];
      s_red[p2][1][i][lane] = acc1[i];
    }
  }
  __syncthreads();
  if (th == 0) {
    const bool zero = (y == 127) || (px == 127);
    const size_t pixb = (((size_t)(n * 128 + y)) * 128 + px) * 64;
#pragma unroll
    for (int ot = 0; ot < 2; ++ot) {
      f32x16 A = ot ? acc1 : acc0;
#pragma unroll
      for (int q = 0; q < 4; ++q) {
        int oo = ot * 32 + 8 * q + 4 * h;
        float v[4];
#pragma unroll
        for (int r = 0; r < 4; ++r)
          v[r] = zero ? 0.f : (A[q * 4 + r] + s_red[p2][ot][q * 4 + r][lane] + bias[oo + r]);
        ushort4 hh;
        hh.x = f2b(v[0]); hh.y = f2b(v[1]); hh.z = f2b(v[2]); hh.w = f2b(v[3]);
        *(ushort4*)(outH + pixb + oo) = hh;
      }
    }
  }
}

// ---------------------------------------------------------------------------
// MFMA 3x3 conv, pad=1, direct-global-load (unchanged — validated).
// ---------------------------------------------------------------------------
template <int NSEG>
__global__ __launch_bounds__(512) void mfconv_d(
    const u16* __restrict__ in0, const u16* __restrict__ in1,
    const u16* __restrict__ in2, const u16* __restrict__ wpk,
    const float* __restrict__ bias, const u16* __restrict__ resh,
    float* __restrict__ outF, u16* __restrict__ outH,
    int OT, int O, int mode) {
  __shared__ float s_red[2][3][16][64];
  const int tid = threadIdx.x;
  const int lane = tid & 63;
  const int w = tid >> 6;
  const int p2 = w >> 2;
  const int kq = w & 3;
  const int y = blockIdx.x >> 1;
  const int xh0 = (blockIdx.x & 1) << 6;
  const int ot = blockIdx.y;
  const int n = blockIdx.z;
  const int px = xh0 + (p2 << 5) + (lane & 31);
  const int h = lane >> 5;

  f32x16 acc;
#pragma unroll
  for (int i = 0; i < 16; ++i) acc[i] = 0.f;

#pragma unroll
  for (int s = 0; s < NSEG; ++s) {
    const u16* sp = (s == 0) ? in0 : ((s == 1) ? in1 : in2);
    const u16* bn = sp + ((size_t)n * 128) * 128 * 64;
#pragma unroll
    for (int ky = 0; ky < 3; ++ky) {
      int r = y + ky - 1;
      if ((unsigned)r >= 128u) continue;
      const u16* rp = bn + (size_t)r * (128 * 64);
#pragma unroll
      for (int kx = 0; kx < 3; ++kx) {
        int col = px + kx - 1;
        bool valid = (unsigned)col < 128u;
        int colc = min(max(col, 0), 127);
        const u16* pp = rp + (size_t)colc * 64 + h * 8;
        U16B bf;
        bf.u = *(const uint4*)(pp + kq * 16);
        if (!valid) bf.u = make_uint4(0, 0, 0, 0);
        U16B a;
        a.u = *(const uint4*)(wpk +
              ((size_t)((((s * 3 + ky) * 3 + kx) * 4 + kq) * OT + ot)) * 512 +
              lane * 8);
        acc = __builtin_amdgcn_mfma_f32_32x32x16_bf16(a.v, bf.v, acc, 0, 0, 0);
      }
    }
  }

  if (kq != 0) {
#pragma unroll
    for (int i = 0; i < 16; ++i) s_red[p2][kq - 1][i][lane] = acc[i];
  }
  __syncthreads();
  if (kq == 0) {
#pragma unroll
    for (int i = 0; i < 16; ++i)
      acc[i] += s_red[p2][0][i][lane] + s_red[p2][1][i][lane] + s_red[p2][2][i][lane];
    const size_t pixb = ((size_t)(n * 128 + y)) * 128 + px;
    if (outH) {
#pragma unroll
      for (int q = 0; q < 4; ++q) {
        int oo = ot * 32 + 8 * q + 4 * h;
        float v[4];
#pragma unroll
        for (int r = 0; r < 4; ++r) v[r] = acc[q * 4 + r] + bias[oo + r];
        if (mode == 1) {
#pragma unroll
          for (int r = 0; r < 4; ++r) v[r] = fmaxf(v[r], 0.f);
        } else if (mode == 3) {
          ushort4 rv = *(const ushort4*)(resh + pixb * 64 + oo);
          v[0] += b2f(rv.x); v[1] += b2f(rv.y); v[2] += b2f(rv.z); v[3] += b2f(rv.w);
        }
        ushort4 hh;
        hh.x = f2b(v[0]); hh.y = f2b(v[1]); hh.z = f2b(v[2]); hh.w = f2b(v[3]);
        *(ushort4*)(outH + pixb * 64 + oo) = hh;
      }
    } else {
#pragma unroll
      for (int q = 0; q < 4; ++q) {
        int oo = ot * 32 + 8 * q + 4 * h;
#pragma unroll
        for (int r = 0; r < 4; ++r) {
          int och = oo + r;
          if (och >= O) continue;
          float v = acc[q * 4 + r] + bias[och];
          if (mode == 3) v += b2f(resh[pixb * 64 + och]);
          outF[((size_t)(n * O + och)) * HW + y * 128 + px] = v;
        }
      }
    }
  }
}

// ---------------------------------------------------------------------------
// Fused offset-conv + modulated deformable conv (R7 512-thread shape)
// with ILP batching: loads hoisted into statically-indexed register arrays
// so 6 (phase 1) / 16 (phase 2) gathers are in flight before consumption.
// __launch_bounds__(512,1): VGPR cap 256 (occupancy grid-pinned at 1 blk/CU).
// ---------------------------------------------------------------------------
__global__ __launch_bounds__(512, 1) void deform_fused(
    const u16* __restrict__ in0, const u16* __restrict__ in1,
    const u16* __restrict__ in2, const u16* __restrict__ woff,
    const float* __restrict__ boff, const u16* __restrict__ xh,
    const u16* __restrict__ wdef, const float* __restrict__ bdef,
    u16* __restrict__ outH) {
  __shared__ float s_off[27][128];
  __shared__ float s_red[4][2][16][64];
  const int tid = threadIdx.x;
  const int lane = tid & 63;
  const int w = tid >> 6;
  const int p2 = w >> 1;
  const int kh = w & 1;
  const int y = blockIdx.x;
  const int n = blockIdx.y;
  const int px = (p2 << 5) + (lane & 31);
  const int h = lane >> 5;

  // ---- Phase 1: offset conv (batched loads per (s,ky)) ----
  {
    f32x16 acc;
#pragma unroll
    for (int i = 0; i < 16; ++i) acc[i] = 0.f;
#pragma unroll
    for (int s = 0; s < 3; ++s) {
      const u16* sp = (s == 0) ? in0 : ((s == 1) ? in1 : in2);
      const u16* bn = sp + ((size_t)n * 128) * 128 * 64;
#pragma unroll
      for (int ky = 0; ky < 3; ++ky) {
        int r = y + ky - 1;
        if ((unsigned)r >= 128u) continue;
        const u16* rp = bn + (size_t)r * (128 * 64);
        U16B bb[3][2];
        bool vv[3];
#pragma unroll
        for (int kx = 0; kx < 3; ++kx) {
          int col = px + kx - 1;
          vv[kx] = (unsigned)col < 128u;
          int colc = min(max(col, 0), 127);
          const u16* pp = rp + (size_t)colc * 64 + h * 8;
          bb[kx][0].u = *(const uint4*)(pp + (kh * 2 + 0) * 16);
          bb[kx][1].u = *(const uint4*)(pp + (kh * 2 + 1) * 16);
        }
#pragma unroll
        for (int kx = 0; kx < 3; ++kx) {
#pragma unroll
          for (int k2 = 0; k2 < 2; ++k2) {
            int ks = kh * 2 + k2;
            U16B bf = bb[kx][k2];
            if (!vv[kx]) bf.u = make_uint4(0, 0, 0, 0);
            U16B a;
            a.u = *(const uint4*)(woff +
                  ((size_t)(((s * 3 + ky) * 3 + kx) * 4 + ks)) * 512 + lane * 8);
            acc = __builtin_amdgcn_mfma_f32_32x32x16_bf16(a.v, bf.v, acc, 0, 0, 0);
          }
        }
      }
    }
    if (kh == 1) {
#pragma unroll
      for (int i = 0; i < 16; ++i) s_red[p2][0][i][lane] = acc[i];
    }
    __syncthreads();
    if (kh == 0) {
#pragma unroll
      for (int q = 0; q < 4; ++q) {
#pragma unroll
        for (int r = 0; r < 4; ++r) {
          int och = 8 * q + 4 * h + r;
          if (och < 27) {
            float v = acc[q * 4 + r] + s_red[p2][0][q * 4 + r][lane] + boff[och];
            if (och >= 18) v = 1.f / (1.f + expf(-v));
            s_off[och][px] = v;
          }
        }
      }
    }
  }
  __syncthreads();

  // ---- Phase 2: deform gather + GEMM (batched 16 gathers per tap) ----
  f32x16 acc0, acc1;
#pragma unroll
  for (int i = 0; i < 16; ++i) { acc0[i] = 0.f; acc1[i] = 0.f; }

  const u16* xb = xh + ((size_t)n * HW) * 64;

#pragma unroll
  for (int kk = 0; kk < 5; ++kk) {
    if (kh && kk == 4) break;
    const int k = kh * 5 + kk;
    const int ky = k / 3 - 1, kx = k % 3 - 1;
    float dy = s_off[2 * k][px];
    float dx = s_off[2 * k + 1][px];
    float m = s_off[18 + k][px];
    float py = dy + (float)(y + ky);
    float pxf = dx + (float)(px + kx);
    float fy = floorf(py), fxx = floorf(pxf);
    float wy = py - fy, wx = pxf - fxx;
    int iy0 = (int)fy, ix0 = (int)fxx;
    bool vy0 = (unsigned)iy0 < 128u, vy1 = (unsigned)(iy0 + 1) < 128u;
    bool vx0 = (unsigned)ix0 < 128u, vx1 = (unsigned)(ix0 + 1) < 128u;
    float omwy = 1.f - wy, omwx = 1.f - wx;
    float f00 = (vy0 && vx0) ? omwy * omwx * m : 0.f;
    float f01 = (vy0 && vx1) ? omwy * wx * m : 0.f;
    float f10 = (vy1 && vx0) ? wy * omwx * m : 0.f;
    float f11 = (vy1 && vx1) ? wy * wx * m : 0.f;
    int y0c = min(max(iy0, 0), 127), y1c = min(max(iy0 + 1, 0), 127);
    int x0c = min(max(ix0, 0), 127), x1c = min(max(ix0 + 1, 0), 127);
    const u16* r00 = xb + ((size_t)(y0c * 128 + x0c)) * 64 + h * 8;
    const u16* r01 = xb + ((size_t)(y0c * 128 + x1c)) * 64 + h * 8;
    const u16* r10 = xb + ((size_t)(y1c * 128 + x0c)) * 64 + h * 8;
    const u16* r11 = xb + ((size_t)(y1c * 128 + x1c)) * 64 + h * 8;

    U16B g00[4], g01[4], g10[4], g11[4];
#pragma unroll
    for (int ks = 0; ks < 4; ++ks) {
      g00[ks].u = *(const uint4*)(r00 + ks * 16);
      g01[ks].u = *(const uint4*)(r01 + ks * 16);
      g10[ks].u = *(const uint4*)(r10 + ks * 16);
      g11[ks].u = *(const uint4*)(r11 + ks * 16);
    }
#pragma unroll
    for (int ks = 0; ks < 4; ++ks) {
      unsigned dw[4];
#pragma unroll
      for (int jj = 0; jj < 4; ++jj) {
        float s0 = f00 * b2f(g00[ks].s[2 * jj]) + f01 * b2f(g01[ks].s[2 * jj]) +
                   f10 * b2f(g10[ks].s[2 * jj]) + f11 * b2f(g11[ks].s[2 * jj]);
        float s1 = f00 * b2f(g00[ks].s[2 * jj + 1]) + f01 * b2f(g01[ks].s[2 * jj + 1]) +
                   f10 * b2f(g10[ks].s[2 * jj + 1]) + f11 * b2f(g11[ks].s[2 * jj + 1]);
        dw[jj] = (unsigned)f2b(s0) | ((unsigned)f2b(s1) << 16);
      }
      U16B bf;
      bf.u = make_uint4(dw[0], dw[1], dw[2], dw[3]);
      const u16* wp = wdef + ((size_t)((k * 4 + ks) * 2)) * 512 + lane * 8;
      U16B a0, a1;
      a0.u = *(const uint4*)wp;
      a1.u = *(const uint4*)(wp + 512);
      acc0 = __builtin_amdgcn_mfma_f32_32x32x16_bf16(a0.v, bf.v, acc0, 0, 0, 0);
      acc1 = __builtin_amdgcn_mfma_f32_32x32x16_bf16(a1.v, bf.v, acc1, 0, 0, 0);
    }
  }

  if (kh == 1) {
#pragma unroll
    for (int i = 0; i < 16; ++i) {
      s_red[p2][0][i][lane] = acc0[i];
      s_red[p2][1][i][lane] = acc1[i];
    }
  }
  __syncthreads();
  if (kh == 0) {
    const size_t pixb = (((size_t)(n * 128 + y)) * 128 + px) * 64;
#pragma unroll
    for (int ot = 0; ot < 2; ++ot) {
      f32x16 A = ot ? acc1 : acc0;
#pragma unroll
      for (int q = 0; q < 4; ++q) {
        int oo = ot * 32 + 8 * q + 4 * h;
        float v[4];
#pragma unroll
        for (int r = 0; r < 4; ++r)
          v[r] = A[q * 4 + r] + s_red[p2][ot][q * 4 + r][lane] + bdef[oo + r];
        ushort4 hh;
        hh.x = f2b(v[0]); hh.y = f2b(v[1]); hh.z = f2b(v[2]); hh.w = f2b(v[3]);
        *(ushort4*)(outH + pixb + oo) = hh;
      }
    }
  }
}

// ---------------------------------------------------------------------------
extern "C" void kernel_launch(void* const* d_in, const int* in_sizes, int n_in,
                              void* d_out, int out_size, void* d_ws, size_t ws_size,
                              hipStream_t stream) {
  const float* xd = (const float*)d_in[0];
  const float* xl = (const float*)d_in[1];
  const float* xr = (const float*)d_in[2];
  const float* up_w = (const float*)d_in[3];
  const float* up_b = (const float*)d_in[4];
  const float* offl_w = (const float*)d_in[5];
  const float* offl_b = (const float*)d_in[6];
  const float* dl_w = (const float*)d_in[7];
  const float* dl_b = (const float*)d_in[8];
  const float* offr_w = (const float*)d_in[9];
  const float* offr_b = (const float*)d_in[10];
  const float* dr_w = (const float*)d_in[11];
  const float* dr_b = (const float*)d_in[12];
  const float* cv_w = (const float*)d_in[13];
  const float* cv_b = (const float*)d_in[14];
  const float* rb1_w1 = (const float*)d_in[15];
  const float* rb1_w2 = (const float*)d_in[16];
  const float* rb2_w1 = (const float*)d_in[17];
  const float* rb2_w2 = (const float*)d_in[18];
  const float* rb1_b1 = (const float*)d_in[19];
  const float* rb1_b2 = (const float*)d_in[20];
  const float* rb2_b1 = (const float*)d_in[21];
  const float* rb2_b2 = (const float*)d_in[22];

  float* ws = (float*)d_ws;
  u16* hb = (u16*)(ws + 1769472);
  u16* xlh = hb;                   // 2097152 each
  u16* xrh = hb + 2097152;
  u16* xdph = hb + 4194304;
  u16* xl2h = hb + 6291456;
  u16* xr2h = hb + 8388608;
  u16* t0h = hb + 10485760;
  u16* t1h = hb + 12582912;
  u16* t2h = hb + 14680064;
  u16* t3h = hb + 16777216;
  u16* xdh = hb + 18874368;        // 1048576 (2*64*64*128)
  u16* wcv = hb + 19922944;        // 110592
  u16* wofl = hb + 20033536;       // 55296
  u16* wofr = hb + 20088832;       // 55296
  u16* wr1a = hb + 20144128;       // 36864
  u16* wr1b = hb + 20180992;
  u16* wr2a = hb + 20217856;
  u16* wr2b = hb + 20254720;
  u16* wdl = hb + 20291584;        // 36864
  u16* wdr = hb + 20328448;        // 36864
  u16* wup = hb + 20365312;        // 32768
  float* outp = (float*)d_out;

  hipLaunchKernelGGL(setup_kernel, dim3(2496), dim3(256), 0, stream,
                     dl_w, dr_w, up_w, cv_w, offl_w, offr_w, rb1_w1, rb1_w2,
                     rb2_w1, rb2_w2, wup, wdl, wdr, wcv, wofl, wofr, wr1a,
                     wr1b, wr2a, wr2b, xl, xr, xlh, xrh, xd, xdh);
  hipLaunchKernelGGL(upconv_mf, dim3(128, 2), dim3(512), 0, stream,
                     xdh, wup, up_b, xdph);
  hipLaunchKernelGGL(deform_fused, dim3(128, 2), dim3(512), 0, stream,
                     xlh, xrh, xdph, wofl, offl_b, xlh, wdl, dl_b, xl2h);
  hipLaunchKernelGGL(deform_fused, dim3(128, 2), dim3(512), 0, stream,
                     xl2h, xrh, xdph, wofr, offr_b, xrh, wdr, dr_b, xr2h);
  hipLaunchKernelGGL(mfconv_d<3>, dim3(256, 2, 2), dim3(512), 0, stream,
                     xl2h, xr2h, xdph, wcv, cv_b, (const u16*)nullptr,
                     (float*)nullptr, t0h, 2, 64, 1);
  hipLaunchKernelGGL(mfconv_d<1>, dim3(256, 2, 2), dim3(512), 0, stream,
                     t0h, (const u16*)nullptr, (const u16*)nullptr, wr1a,
                     rb1_b1, (const u16*)nullptr, (float*)nullptr, t1h,
                     2, 64, 1);
  hipLaunchKernelGGL(mfconv_d<1>, dim3(256, 2, 2), dim3(512), 0, stream,
                     t1h, (const u16*)nullptr, (const u16*)nullptr, wr1b,
                     rb1_b2, t0h, (float*)nullptr, t2h, 2, 64, 3);
  hipLaunchKernelGGL(mfconv_d<1>, dim3(256, 2, 2), dim3(512), 0, stream,
                     t2h, (const u16*)nullptr, (const u16*)nullptr, wr2a,
                     rb2_b1, (const u16*)nullptr, (float*)nullptr, t3h,
                     2, 64, 1);
  hipLaunchKernelGGL(mfconv_d<1>, dim3(256, 2, 2), dim3(512), 0, stream,
                     t3h, (const u16*)nullptr, (const u16*)nullptr, wr2b,
                     rb2_b2, t2h, outp, (u16*)nullptr, 2, 64, 3);
}

// Round 11
// 194.003 us; speedup vs baseline: 1.1151x; 1.0000x over previous
//
#include <hip/hip_runtime.h>
#include <math.h>

#define HW 16384

typedef unsigned short u16;
typedef __attribute__((ext_vector_type(8))) short short8;
typedef __attribute__((ext_vector_type(16))) float f32x16;

union U16B {
  uint4 u;
  short8 v;
  u16 s[8];
};

__device__ inline u16 f2b(float f) {
  unsigned u = __float_as_uint(f);
  u += 0x7FFF + ((u >> 16) & 1);
  return (u16)(u >> 16);
}
__device__ inline float b2f(u16 h) {
  return __uint_as_float(((unsigned)h) << 16);
}

// ---------------------------------------------------------------------------
// Weight packing helpers (bf16 per-lane MFMA A-fragments).
// ---------------------------------------------------------------------------
__device__ inline u16 pack_frag(const float* __restrict__ w, int Cin, int O,
                                int OT, int d) {
  int j = d & 7;
  int lane = (d >> 3) & 63;
  int rest = d >> 9;
  int ot = rest % OT; rest /= OT;
  int ks = rest & 3; rest >>= 2;
  int kx = rest % 3; rest /= 3;
  int ky = rest % 3; int s = rest / 3;
  int och = ot * 32 + (lane & 31);
  int ch = s * 64 + ks * 16 + ((lane >> 5) << 3) + j;
  if (och >= O) return 0;
  return f2b(w[((size_t)och * Cin + ch) * 9 + ky * 3 + kx]);
}

__device__ inline u16 pack_def(const float* __restrict__ w, int d) {
  int j = d & 7;
  int lane = (d >> 3) & 63;
  int g = d >> 9;
  int ot = g & 1;
  int t = g >> 1;
  int ks = t & 3;
  int k = t >> 2;
  int och = ot * 32 + (lane & 31);
  int c = ks * 16 + ((lane >> 5) << 3) + j;
  return f2b(w[((size_t)och * 64 + c) * 9 + k]);
}

__device__ inline u16 pack_up(const float* __restrict__ w, int d) {
  int j = d & 7;
  int lane = (d >> 3) & 63;
  int g = d >> 9;
  int ot = g & 1;
  int rest = g >> 1;
  int ks = rest & 7;
  int t = rest >> 3;
  int och = ot * 32 + (lane & 31);
  int ci = ks * 16 + ((lane >> 5) << 3) + j;
  return f2b(w[((size_t)och * 128 + ci) * 4 + t]);
}

// ---------------------------------------------------------------------------
// setup_kernel = prep (weight packing) + cvt_nhwc (xl,xr) + cvt_xd, one launch.
// (unchanged — validated)
// ---------------------------------------------------------------------------
__global__ __launch_bounds__(256) void setup_kernel(
    const float* __restrict__ dl_w, const float* __restrict__ dr_w,
    const float* __restrict__ up_w, const float* __restrict__ cv_w,
    const float* __restrict__ offl_w, const float* __restrict__ offr_w,
    const float* __restrict__ r1a, const float* __restrict__ r1b,
    const float* __restrict__ r2a, const float* __restrict__ r2b,
    u16* __restrict__ wup, u16* __restrict__ wdl, u16* __restrict__ wdr,
    u16* __restrict__ wcv, u16* __restrict__ wofl, u16* __restrict__ wofr,
    u16* __restrict__ wr1a, u16* __restrict__ wr1b,
    u16* __restrict__ wr2a, u16* __restrict__ wr2b,
    const float* __restrict__ xl, const float* __restrict__ xr,
    u16* __restrict__ xlh, u16* __restrict__ xrh,
    const float* __restrict__ xd, u16* __restrict__ xdh) {
  __shared__ float sT[8448];
  int tid = threadIdx.x;
  int b = blockIdx.x;
  if (b < 1856) {
    int d = b * 256 + tid;
    if (d < 32768) { wup[d] = pack_up(up_w, d); return; }
    d -= 32768;
    if (d < 36864) { wdl[d] = pack_def(dl_w, d); return; }
    d -= 36864;
    if (d < 36864) { wdr[d] = pack_def(dr_w, d); return; }
    d -= 36864;
    if (d < 110592) { wcv[d] = pack_frag(cv_w, 192, 64, 2, d); return; }
    d -= 110592;
    if (d < 55296) { wofl[d] = pack_frag(offl_w, 192, 27, 1, d); return; }
    d -= 55296;
    if (d < 55296) { wofr[d] = pack_frag(offr_w, 192, 27, 1, d); return; }
    d -= 55296;
    if (d < 36864) { wr1a[d] = pack_frag(r1a, 64, 64, 2, d); return; }
    d -= 36864;
    if (d < 36864) { wr1b[d] = pack_frag(r1b, 64, 64, 2, d); return; }
    d -= 36864;
    if (d < 36864) { wr2a[d] = pack_frag(r2a, 64, 64, 2, d); return; }
    d -= 36864;
    if (d < 36864) { wr2b[d] = pack_frag(r2b, 64, 64, 2, d); return; }
    return;
  }
  b -= 1856;
  if (b < 512) {
    int y = b & 127;
    int pid = b >> 7;
    const float* src = (pid >> 1) ? xr : xl;
    u16* dst = (pid >> 1) ? xrh : xlh;
    int n = pid & 1;
#pragma unroll
    for (int i = 0; i < 8; ++i) {
      int q = tid + i * 256;
      int ch = q >> 5, pxq = q & 31;
      float4 v = *(const float4*)(src + ((size_t)(n * 64 + ch)) * HW + y * 128 + pxq * 4);
      *(float4*)&sT[ch * 132 + pxq * 4] = v;
    }
    __syncthreads();
    int px = tid >> 1, half = tid & 1;
    u16* op = dst + (((size_t)(n * 128 + y)) * 128 + px) * 64 + half * 32;
#pragma unroll
    for (int c = 0; c < 4; ++c) {
      uint4 v;
      int ob = (half * 32 + c * 8);
      v.x = (unsigned)f2b(sT[(ob + 0) * 132 + px]) | ((unsigned)f2b(sT[(ob + 1) * 132 + px]) << 16);
      v.y = (unsigned)f2b(sT[(ob + 2) * 132 + px]) | ((unsigned)f2b(sT[(ob + 3) * 132 + px]) << 16);
      v.z = (unsigned)f2b(sT[(ob + 4) * 132 + px]) | ((unsigned)f2b(sT[(ob + 5) * 132 + px]) << 16);
      v.w = (unsigned)f2b(sT[(ob + 6) * 132 + px]) | ((unsigned)f2b(sT[(ob + 7) * 132 + px]) << 16);
      *(uint4*)(op + c * 8) = v;
    }
    return;
  }
  b -= 512;
  {
    int r = b & 63;
    int n = b >> 6;
#pragma unroll
    for (int i = 0; i < 8; ++i) {
      int q = tid + i * 256;
      int ch = q >> 4, col4 = q & 15;
      float4 v = *(const float4*)(xd + ((size_t)(n * 128 + ch) * 64 + r) * 64 + col4 * 4);
      *(float4*)&sT[ch * 66 + col4 * 4] = v;
    }
    __syncthreads();
#pragma unroll
    for (int i = 0; i < 4; ++i) {
      int q = tid + i * 256;
      int col = q >> 4, cho = q & 15;
      uint4 v;
      int cb = cho * 8;
      v.x = (unsigned)f2b(sT[(cb + 0) * 66 + col]) | ((unsigned)f2b(sT[(cb + 1) * 66 + col]) << 16);
      v.y = (unsigned)f2b(sT[(cb + 2) * 66 + col]) | ((unsigned)f2b(sT[(cb + 3) * 66 + col]) << 16);
      v.z = (unsigned)f2b(sT[(cb + 4) * 66 + col]) | ((unsigned)f2b(sT[(cb + 5) * 66 + col]) << 16);
      v.w = (unsigned)f2b(sT[(cb + 6) * 66 + col]) | ((unsigned)f2b(sT[(cb + 7) * 66 + col]) << 16);
      *(uint4*)(xdh + (((size_t)(n * 64 + r)) * 64 + col) * 128 + cb) = v;
    }
  }
}

// ---------------------------------------------------------------------------
// Fused nearest-x2 upsample + 2x2 conv + zero-pad via gather + MFMA.
// (unchanged — validated)
// ---------------------------------------------------------------------------
__global__ __launch_bounds__(512) void upconv_mf(
    const u16* __restrict__ xdh, const u16* __restrict__ wup,
    const float* __restrict__ bias, u16* __restrict__ outH) {
  __shared__ float s_red[4][2][16][64];
  const int tid = threadIdx.x;
  const int lane = tid & 63;
  const int w = tid >> 6;
  const int p2 = w >> 1;
  const int th = w & 1;
  const int y = blockIdx.x;
  const int n = blockIdx.y;
  const int px = (p2 << 5) + (lane & 31);
  const int h = lane >> 5;

  f32x16 acc0, acc1;
#pragma unroll
  for (int i = 0; i < 16; ++i) { acc0[i] = 0.f; acc1[i] = 0.f; }

  const u16* xb = xdh + ((size_t)n * 64 * 64) * 128;

#pragma unroll
  for (int tt = 0; tt < 2; ++tt) {
    const int t = th * 2 + tt;
    const int ty = t >> 1, tx = t & 1;
    const int row = min((y + ty) >> 1, 63);
    const int col = min((px + tx) >> 1, 63);
    const u16* src = xb + ((size_t)(row * 64 + col)) * 128;
#pragma unroll
    for (int ks = 0; ks < 8; ++ks) {
      U16B bf;
      bf.u = *(const uint4*)(src + ks * 16 + h * 8);
      const u16* wp = wup + ((size_t)((t * 8 + ks) * 2)) * 512 + lane * 8;
      U16B a0, a1;
      a0.u = *(const uint4*)wp;
      a1.u = *(const uint4*)(wp + 512);
      acc0 = __builtin_amdgcn_mfma_f32_32x32x16_bf16(a0.v, bf.v, acc0, 0, 0, 0);
      acc1 = __builtin_amdgcn_mfma_f32_32x32x16_bf16(a1.v, bf.v, acc1, 0, 0, 0);
    }
  }

  if (th == 1) {
#pragma unroll
    for (int i = 0; i < 16; ++i) {
      s_red[p2][0][i][lane] = acc0[i];
      s_red[p2][1][i][lane] = acc1[i];
    }
  }
  __syncthreads();
  if (th == 0) {
    const bool zero = (y == 127) || (px == 127);
    const size_t pixb = (((size_t)(n * 128 + y)) * 128 + px) * 64;
#pragma unroll
    for (int ot = 0; ot < 2; ++ot) {
      f32x16 A = ot ? acc1 : acc0;
#pragma unroll
      for (int q = 0; q < 4; ++q) {
        int oo = ot * 32 + 8 * q + 4 * h;
        float v[4];
#pragma unroll
        for (int r = 0; r < 4; ++r)
          v[r] = zero ? 0.f : (A[q * 4 + r] + s_red[p2][ot][q * 4 + r][lane] + bias[oo + r]);
        ushort4 hh;
        hh.x = f2b(v[0]); hh.y = f2b(v[1]); hh.z = f2b(v[2]); hh.w = f2b(v[3]);
        *(ushort4*)(outH + pixb + oo) = hh;
      }
    }
  }
}

// ---------------------------------------------------------------------------
// MFMA 3x3 conv, pad=1, direct-global-load with per-segment ILP batching:
// all 9 input gathers + 9 weight frags issued before the 9 MFMAs.
// Block = 64 px x 32 och: 512 thr = 8 waves = 2 px-tiles x 4 ks-quarters.
// grid = (256 rowhalves, OT, n). __launch_bounds__(512,2) caps VGPR at 128.
// ---------------------------------------------------------------------------
template <int NSEG>
__global__ __launch_bounds__(512, 2) void mfconv_d(
    const u16* __restrict__ in0, const u16* __restrict__ in1,
    const u16* __restrict__ in2, const u16* __restrict__ wpk,
    const float* __restrict__ bias, const u16* __restrict__ resh,
    float* __restrict__ outF, u16* __restrict__ outH,
    int OT, int O, int mode) {
  __shared__ float s_red[2][3][16][64];
  const int tid = threadIdx.x;
  const int lane = tid & 63;
  const int w = tid >> 6;
  const int p2 = w >> 2;
  const int kq = w & 3;
  const int y = blockIdx.x >> 1;
  const int xh0 = (blockIdx.x & 1) << 6;
  const int ot = blockIdx.y;
  const int n = blockIdx.z;
  const int px = xh0 + (p2 << 5) + (lane & 31);
  const int h = lane >> 5;

  f32x16 acc;
#pragma unroll
  for (int i = 0; i < 16; ++i) acc[i] = 0.f;

#pragma unroll
  for (int s = 0; s < NSEG; ++s) {
    const u16* sp = (s == 0) ? in0 : ((s == 1) ? in1 : in2);
    const u16* bn = sp + ((size_t)n * 128) * 128 * 64;
    U16B bb[9], aa[9];
    bool vz[9];
#pragma unroll
    for (int t = 0; t < 9; ++t) {
      const int ky = t / 3, kx = t % 3;
      int r = y + ky - 1;
      int col = px + kx - 1;
      vz[t] = ((unsigned)r < 128u) && ((unsigned)col < 128u);
      int rc = min(max(r, 0), 127);
      int cc = min(max(col, 0), 127);
      bb[t].u = *(const uint4*)(bn + (size_t)rc * (128 * 64) + (size_t)cc * 64 +
                                h * 8 + kq * 16);
      aa[t].u = *(const uint4*)(wpk +
            ((size_t)((((s * 3 + ky) * 3 + kx) * 4 + kq) * OT + ot)) * 512 +
            lane * 8);
    }
#pragma unroll
    for (int t = 0; t < 9; ++t) {
      U16B bf = bb[t];
      if (!vz[t]) bf.u = make_uint4(0, 0, 0, 0);
      acc = __builtin_amdgcn_mfma_f32_32x32x16_bf16(aa[t].v, bf.v, acc, 0, 0, 0);
    }
  }

  if (kq != 0) {
#pragma unroll
    for (int i = 0; i < 16; ++i) s_red[p2][kq - 1][i][lane] = acc[i];
  }
  __syncthreads();
  if (kq == 0) {
#pragma unroll
    for (int i = 0; i < 16; ++i)
      acc[i] += s_red[p2][0][i][lane] + s_red[p2][1][i][lane] + s_red[p2][2][i][lane];
    const size_t pixb = ((size_t)(n * 128 + y)) * 128 + px;
    if (outH) {
#pragma unroll
      for (int q = 0; q < 4; ++q) {
        int oo = ot * 32 + 8 * q + 4 * h;
        float v[4];
#pragma unroll
        for (int r = 0; r < 4; ++r) v[r] = acc[q * 4 + r] + bias[oo + r];
        if (mode == 1) {
#pragma unroll
          for (int r = 0; r < 4; ++r) v[r] = fmaxf(v[r], 0.f);
        } else if (mode == 3) {
          ushort4 rv = *(const ushort4*)(resh + pixb * 64 + oo);
          v[0] += b2f(rv.x); v[1] += b2f(rv.y); v[2] += b2f(rv.z); v[3] += b2f(rv.w);
        }
        ushort4 hh;
        hh.x = f2b(v[0]); hh.y = f2b(v[1]); hh.z = f2b(v[2]); hh.w = f2b(v[3]);
        *(ushort4*)(outH + pixb * 64 + oo) = hh;
      }
    } else {
#pragma unroll
      for (int q = 0; q < 4; ++q) {
        int oo = ot * 32 + 8 * q + 4 * h;
#pragma unroll
        for (int r = 0; r < 4; ++r) {
          int och = oo + r;
          if (och >= O) continue;
          float v = acc[q * 4 + r] + bias[och];
          if (mode == 3) v += b2f(resh[pixb * 64 + och]);
          outF[((size_t)(n * O + och)) * HW + y * 128 + px] = v;
        }
      }
    }
  }
}

// ---------------------------------------------------------------------------
// Fused offset-conv + modulated deformable conv (unchanged from R9 —
// validated: ILP-batched, __launch_bounds__(512,1)).
// ---------------------------------------------------------------------------
__global__ __launch_bounds__(512, 1) void deform_fused(
    const u16* __restrict__ in0, const u16* __restrict__ in1,
    const u16* __restrict__ in2, const u16* __restrict__ woff,
    const float* __restrict__ boff, const u16* __restrict__ xh,
    const u16* __restrict__ wdef, const float* __restrict__ bdef,
    u16* __restrict__ outH) {
  __shared__ float s_off[27][128];
  __shared__ float s_red[4][2][16][64];
  const int tid = threadIdx.x;
  const int lane = tid & 63;
  const int w = tid >> 6;
  const int p2 = w >> 1;
  const int kh = w & 1;
  const int y = blockIdx.x;
  const int n = blockIdx.y;
  const int px = (p2 << 5) + (lane & 31);
  const int h = lane >> 5;

  // ---- Phase 1: offset conv (batched loads per (s,ky)) ----
  {
    f32x16 acc;
#pragma unroll
    for (int i = 0; i < 16; ++i) acc[i] = 0.f;
#pragma unroll
    for (int s = 0; s < 3; ++s) {
      const u16* sp = (s == 0) ? in0 : ((s == 1) ? in1 : in2);
      const u16* bn = sp + ((size_t)n * 128) * 128 * 64;
#pragma unroll
      for (int ky = 0; ky < 3; ++ky) {
        int r = y + ky - 1;
        if ((unsigned)r >= 128u) continue;
        const u16* rp = bn + (size_t)r * (128 * 64);
        U16B bb[3][2];
        bool vv[3];
#pragma unroll
        for (int kx = 0; kx < 3; ++kx) {
          int col = px + kx - 1;
          vv[kx] = (unsigned)col < 128u;
          int colc = min(max(col, 0), 127);
          const u16* pp = rp + (size_t)colc * 64 + h * 8;
          bb[kx][0].u = *(const uint4*)(pp + (kh * 2 + 0) * 16);
          bb[kx][1].u = *(const uint4*)(pp + (kh * 2 + 1) * 16);
        }
#pragma unroll
        for (int kx = 0; kx < 3; ++kx) {
#pragma unroll
          for (int k2 = 0; k2 < 2; ++k2) {
            int ks = kh * 2 + k2;
            U16B bf = bb[kx][k2];
            if (!vv[kx]) bf.u = make_uint4(0, 0, 0, 0);
            U16B a;
            a.u = *(const uint4*)(woff +
                  ((size_t)(((s * 3 + ky) * 3 + kx) * 4 + ks)) * 512 + lane * 8);
            acc = __builtin_amdgcn_mfma_f32_32x32x16_bf16(a.v, bf.v, acc, 0, 0, 0);
          }
        }
      }
    }
    if (kh == 1) {
#pragma unroll
      for (int i = 0; i < 16; ++i) s_red[p2][0][i][lane] = acc[i];
    }
    __syncthreads();
    if (kh == 0) {
#pragma unroll
      for (int q = 0; q < 4; ++q) {
#pragma unroll
        for (int r = 0; r < 4; ++r) {
          int och = 8 * q + 4 * h + r;
          if (och < 27) {
            float v = acc[q * 4 + r] + s_red[p2][0][q * 4 + r][lane] + boff[och];
            if (och >= 18) v = 1.f / (1.f + expf(-v));
            s_off[och][px] = v;
          }
        }
      }
    }
  }
  __syncthreads();

  // ---- Phase 2: deform gather + GEMM (batched 16 gathers per tap) ----
  f32x16 acc0, acc1;
#pragma unroll
  for (int i = 0; i < 16; ++i) { acc0[i] = 0.f; acc1[i] = 0.f; }

  const u16* xb = xh + ((size_t)n * HW) * 64;

#pragma unroll
  for (int kk = 0; kk < 5; ++kk) {
    if (kh && kk == 4) break;
    const int k = kh * 5 + kk;
    const int ky = k / 3 - 1, kx = k % 3 - 1;
    float dy = s_off[2 * k][px];
    float dx = s_off[2 * k + 1][px];
    float m = s_off[18 + k][px];
    float py = dy + (float)(y + ky);
    float pxf = dx + (float)(px + kx);
    float fy = floorf(py), fxx = floorf(pxf);
    float wy = py - fy, wx = pxf - fxx;
    int iy0 = (int)fy, ix0 = (int)fxx;
    bool vy0 = (unsigned)iy0 < 128u, vy1 = (unsigned)(iy0 + 1) < 128u;
    bool vx0 = (unsigned)ix0 < 128u, vx1 = (unsigned)(ix0 + 1) < 128u;
    float omwy = 1.f - wy, omwx = 1.f - wx;
    float f00 = (vy0 && vx0) ? omwy * omwx * m : 0.f;
    float f01 = (vy0 && vx1) ? omwy * wx * m : 0.f;
    float f10 = (vy1 && vx0) ? wy * omwx * m : 0.f;
    float f11 = (vy1 && vx1) ? wy * wx * m : 0.f;
    int y0c = min(max(iy0, 0), 127), y1c = min(max(iy0 + 1, 0), 127);
    int x0c = min(max(ix0, 0), 127), x1c = min(max(ix0 + 1, 0), 127);
    const u16* r00 = xb + ((size_t)(y0c * 128 + x0c)) * 64 + h * 8;
    const u16* r01 = xb + ((size_t)(y0c * 128 + x1c)) * 64 + h * 8;
    const u16* r10 = xb + ((size_t)(y1c * 128 + x0c)) * 64 + h * 8;
    const u16* r11 = xb + ((size_t)(y1c * 128 + x1c)) * 64 + h * 8;

    U16B g00[4], g01[4], g10[4], g11[4];
#pragma unroll
    for (int ks = 0; ks < 4; ++ks) {
      g00[ks].u = *(const uint4*)(r00 + ks * 16);
      g01[ks].u = *(const uint4*)(r01 + ks * 16);
      g10[ks].u = *(const uint4*)(r10 + ks * 16);
      g11[ks].u = *(const uint4*)(r11 + ks * 16);
    }
#pragma unroll
    for (int ks = 0; ks < 4; ++ks) {
      unsigned dw[4];
#pragma unroll
      for (int jj = 0; jj < 4; ++jj) {
        float s0 = f00 * b2f(g00[ks].s[2 * jj]) + f01 * b2f(g01[ks].s[2 * jj]) +
                   f10 * b2f(g10[ks].s[2 * jj]) + f11 * b2f(g11[ks].s[2 * jj]);
        float s1 = f00 * b2f(g00[ks].s[2 * jj + 1]) + f01 * b2f(g01[ks].s[2 * jj + 1]) +
                   f10 * b2f(g10[ks].s[2 * jj + 1]) + f11 * b2f(g11[ks].s[2 * jj + 1]);
        dw[jj] = (unsigned)f2b(s0) | ((unsigned)f2b(s1) << 16);
      }
      U16B bf;
      bf.u = make_uint4(dw[0], dw[1], dw[2], dw[3]);
      const u16* wp = wdef + ((size_t)((k * 4 + ks) * 2)) * 512 + lane * 8;
      U16B a0, a1;
      a0.u = *(const uint4*)wp;
      a1.u = *(const uint4*)(wp + 512);
      acc0 = __builtin_amdgcn_mfma_f32_32x32x16_bf16(a0.v, bf.v, acc0, 0, 0, 0);
      acc1 = __builtin_amdgcn_mfma_f32_32x32x16_bf16(a1.v, bf.v, acc1, 0, 0, 0);
    }
  }

  if (kh == 1) {
#pragma unroll
    for (int i = 0; i < 16; ++i) {
      s_red[p2][0][i][lane] = acc0[i];
      s_red[p2][1][i][lane] = acc1[i];
    }
  }
  __syncthreads();
  if (kh == 0) {
    const size_t pixb = (((size_t)(n * 128 + y)) * 128 + px) * 64;
#pragma unroll
    for (int ot = 0; ot < 2; ++ot) {
      f32x16 A = ot ? acc1 : acc0;
#pragma unroll
      for (int q = 0; q < 4; ++q) {
        int oo = ot * 32 + 8 * q + 4 * h;
        float v[4];
#pragma unroll
        for (int r = 0; r < 4; ++r)
          v[r] = A[q * 4 + r] + s_red[p2][ot][q * 4 + r][lane] + bdef[oo + r];
        ushort4 hh;
        hh.x = f2b(v[0]); hh.y = f2b(v[1]); hh.z = f2b(v[2]); hh.w = f2b(v[3]);
        *(ushort4*)(outH + pixb + oo) = hh;
      }
    }
  }
}

// ---------------------------------------------------------------------------
extern "C" void kernel_launch(void* const* d_in, const int* in_sizes, int n_in,
                              void* d_out, int out_size, void* d_ws, size_t ws_size,
                              hipStream_t stream) {
  const float* xd = (const float*)d_in[0];
  const float* xl = (const float*)d_in[1];
  const float* xr = (const float*)d_in[2];
  const float* up_w = (const float*)d_in[3];
  const float* up_b = (const float*)d_in[4];
  const float* offl_w = (const float*)d_in[5];
  const float* offl_b = (const float*)d_in[6];
  const float* dl_w = (const float*)d_in[7];
  const float* dl_b = (const float*)d_in[8];
  const float* offr_w = (const float*)d_in[9];
  const float* offr_b = (const float*)d_in[10];
  const float* dr_w = (const float*)d_in[11];
  const float* dr_b = (const float*)d_in[12];
  const float* cv_w = (const float*)d_in[13];
  const float* cv_b = (const float*)d_in[14];
  const float* rb1_w1 = (const float*)d_in[15];
  const float* rb1_w2 = (const float*)d_in[16];
  const float* rb2_w1 = (const float*)d_in[17];
  const float* rb2_w2 = (const float*)d_in[18];
  const float* rb1_b1 = (const float*)d_in[19];
  const float* rb1_b2 = (const float*)d_in[20];
  const float* rb2_b1 = (const float*)d_in[21];
  const float* rb2_b2 = (const float*)d_in[22];

  float* ws = (float*)d_ws;
  u16* hb = (u16*)(ws + 1769472);
  u16* xlh = hb;                   // 2097152 each
  u16* xrh = hb + 2097152;
  u16* xdph = hb + 4194304;
  u16* xl2h = hb + 6291456;
  u16* xr2h = hb + 8388608;
  u16* t0h = hb + 10485760;
  u16* t1h = hb + 12582912;
  u16* t2h = hb + 14680064;
  u16* t3h = hb + 16777216;
  u16* xdh = hb + 18874368;        // 1048576 (2*64*64*128)
  u16* wcv = hb + 19922944;        // 110592
  u16* wofl = hb + 20033536;       // 55296
  u16* wofr = hb + 20088832;       // 55296
  u16* wr1a = hb + 20144128;       // 36864
  u16* wr1b = hb + 20180992;
  u16* wr2a = hb + 20217856;
  u16* wr2b = hb + 20254720;
  u16* wdl = hb + 20291584;        // 36864
  u16* wdr = hb + 20328448;        // 36864
  u16* wup = hb + 20365312;        // 32768
  float* outp = (float*)d_out;

  hipLaunchKernelGGL(setup_kernel, dim3(2496), dim3(256), 0, stream,
                     dl_w, dr_w, up_w, cv_w, offl_w, offr_w, rb1_w1, rb1_w2,
                     rb2_w1, rb2_w2, wup, wdl, wdr, wcv, wofl, wofr, wr1a,
                     wr1b, wr2a, wr2b, xl, xr, xlh, xrh, xd, xdh);
  hipLaunchKernelGGL(upconv_mf, dim3(128, 2), dim3(512), 0, stream,
                     xdh, wup, up_b, xdph);
  hipLaunchKernelGGL(deform_fused, dim3(128, 2), dim3(512), 0, stream,
                     xlh, xrh, xdph, wofl, offl_b, xlh, wdl, dl_b, xl2h);
  hipLaunchKernelGGL(deform_fused, dim3(128, 2), dim3(512), 0, stream,
                     xl2h, xrh, xdph, wofr, offr_b, xrh, wdr, dr_b, xr2h);
  hipLaunchKernelGGL(mfconv_d<3>, dim3(256, 2, 2), dim3(512), 0, stream,
                     xl2h, xr2h, xdph, wcv, cv_b, (const u16*)nullptr,
                     (float*)nullptr, t0h, 2, 64, 1);
  hipLaunchKernelGGL(mfconv_d<1>, dim3(256, 2, 2), dim3(512), 0, stream,
                     t0h, (const u16*)nullptr, (const u16*)nullptr, wr1a,
                     rb1_b1, (const u16*)nullptr, (float*)nullptr, t1h,
                     2, 64, 1);
  hipLaunchKernelGGL(mfconv_d<1>, dim3(256, 2, 2), dim3(512), 0, stream,
                     t1h, (const u16*)nullptr, (const u16*)nullptr, wr1b,
                     rb1_b2, t0h, (float*)nullptr, t2h, 2, 64, 3);
  hipLaunchKernelGGL(mfconv_d<1>, dim3(256, 2, 2), dim3(512), 0, stream,
                     t2h, (const u16*)nullptr, (const u16*)nullptr, wr2a,
                     rb2_b1, (const u16*)nullptr, (float*)nullptr, t3h,
                     2, 64, 1);
  hipLaunchKernelGGL(mfconv_d<1>, dim3(256, 2, 2), dim3(512), 0, stream,
                     t3h, (const u16*)nullptr, (const u16*)nullptr, wr2b,
                     rb2_b2, t2h, outp, (u16*)nullptr, 2, 64, 3);
}